// Round 4
// baseline (538.364 us; speedup 1.0000x reference)
//
#include <hip/hip_runtime.h>

#define H 1024
#define LSEQ 2048
#define M_TOT 32768          // B*L
#define KDIM 2048            // 2H
#define NKT 32               // K tiles of 64
#define NCT 8                // col tiles of 128
#define NEG_INF_F (-10000000000.0f)

typedef _Float16 f16;
typedef f16 f16x4 __attribute__((ext_vector_type(4)));
typedef f16 f16x8 __attribute__((ext_vector_type(8)));
typedef float f32x4 __attribute__((ext_vector_type(4)));

// ---------------- ws layout ----------------
#define WS_WE16_OFF   0
#define WS_SDEC_OFF   (4u << 20)
#define WS_PART_OFF   ((4u << 20) + (64u << 10))

// Convert W_e = attn_w[:, H:3H] to fp16, layout [h][e] row-major.
__global__ void wecvt_kernel(const float* __restrict__ attn_w, f16* __restrict__ we16) {
    int idx = blockIdx.x * 256 + threadIdx.x;
    int h  = idx >> 9;
    int e4 = idx & 511;
    const float4 v4 = *reinterpret_cast<const float4*>(attn_w + (size_t)h * 3072 + 1024 + e4 * 4);
    f16x4 hv = { (f16)v4.x, (f16)v4.y, (f16)v4.z, (f16)v4.w };
    *reinterpret_cast<f16x4*>(we16 + (size_t)h * 2048 + e4 * 4) = hv;
}

// score_dec[b][h] = attn_b[h] + sum_k v[b][k] * attn_w[h][k]
__global__ void sdec_kernel(const float* __restrict__ v,
                            const float* __restrict__ attn_w,
                            const float* __restrict__ attn_b,
                            float* __restrict__ sdec) {
    int gid  = blockIdx.x * 4 + (threadIdx.x >> 6);
    int lane = threadIdx.x & 63;
    int b = gid >> 10;
    int h = gid & 1023;
    const float* vr = v + b * 1024;
    const float* wr = attn_w + (size_t)h * 3072;
    float s = 0.f;
    #pragma unroll 4
    for (int k = lane; k < 1024; k += 64) s += vr[k] * wr[k];
    #pragma unroll
    for (int m = 1; m < 64; m <<= 1) s += __shfl_xor(s, m);
    if (lane == 0) sdec[b * 1024 + h] = s + attn_b[h];
}

// Main fused kernel: 256x128 tile, 8 waves (4M x 2N), BK=64, 1 block/CU.
// A: fp32 global -> reg (issue-early) -> cvt fp16 -> swizzled LDS (dbuf).
// B: fp16 global (L2/L1-resident) -> reg fragments (reg dbuf).
// Raw s_barrier (no vmcnt drain) + explicit lgkmcnt(0).
__global__ __launch_bounds__(512, 2) void fused_gemm(
        const float* __restrict__ enc,    // [32768][2048] fp32
        const f16*  __restrict__ we16,    // [1024][2048] fp16
        const float* __restrict__ sdec,   // [16][1024]
        const float* __restrict__ vw,     // [1024]
        float* __restrict__ part)         // [NCT][32768]
{
    // chunked XCD remap: 1024 blocks, 8 XCDs, 128 per chunk (bijective).
    const int bid = blockIdx.x;
    const int logical = (bid & 7) * 128 + (bid >> 3);
    const int rt = logical >> 3;     // row tile (256 rows)
    const int ct = logical & 7;      // col tile (128 cols)

    const int tid = threadIdx.x;
    const int l   = tid & 63;
    const int wv  = tid >> 6;        // 0..7
    const int wm  = wv >> 1;         // 0..3 (64 rows each)
    const int wn  = wv & 1;          // 0..1 (64 cols each)
    const int l15 = l & 15;
    const int l4  = l >> 4;

    __shared__ f16 As[2][256][64];   // 128B rows, 16B-slot XOR swizzle: slot^(row&7)
    __shared__ float red[2][256];

    const int rowbase = rt * 256;
    const int colbase = ct * 128;
    const int bidx = rt >> 3;        // 256-row tile / 2048-row batch

    // ---- A staging: thread covers rows {tid>>4 + 32c, c=0..7}, float4 col tid&15 ----
    const int arow   = tid >> 4;
    const int acol16 = tid & 15;
    const float* aBase = enc + (size_t)(rowbase + arow) * KDIM + acol16 * 4;
    // swizzled write byte offset (row&7 == arow&7 for all c since 32c%8==0)
    const int wbyte = arow * 128 + (((acol16 >> 1) ^ (arow & 7)) << 4) + (acol16 & 1) * 8;

    // ---- A fragment reads (swizzled): frag(i,kh) row=wm*64+i*16+l15, slot=(kh*4+l4)^(l15&7)
    const int slotA  = l4 ^ (l15 & 7);
    const int rbyte0 = (wm * 64 + l15) * 128 + (slotA << 4);
    const int rbyte1 = (wm * 64 + l15) * 128 + ((slotA ^ 4) << 4);

    // B fragment base: bf[j] <- we16[(colbase + wn*64 + j*16 + l15)][t*64 + kh*32 + l4*8]
    const f16* bptr = we16 + (size_t)(colbase + wn * 64 + l15) * KDIM + l4 * 8;

    f32x4 acc[4][4] = {};
    f16x8 bfc[8];

    auto stageIssue = [&](float4 (&ar)[8], int t) {
        const float* p = aBase + t * 64;
        #pragma unroll
        for (int c = 0; c < 8; ++c)
            ar[c] = *reinterpret_cast<const float4*>(p + (size_t)(32 * c) * KDIM);
    };
    auto stageWrite = [&](const float4 (&ar)[8], int NXT) {
        char* b = (char*)&As[0][0][0] + NXT * 32768 + wbyte;
        #pragma unroll
        for (int c = 0; c < 8; ++c) {
            f16x4 hv = { (f16)ar[c].x, (f16)ar[c].y, (f16)ar[c].z, (f16)ar[c].w };
            *reinterpret_cast<f16x4*>(b + c * 32 * 128) = hv;   // ds_write_b64
        }
    };
    auto loadB = [&](f16x8 (&bf)[8], int t) {
        const f16* p = bptr + t * 64;
        #pragma unroll
        for (int j = 0; j < 4; ++j) {
            bf[j]     = *reinterpret_cast<const f16x8*>(p + (size_t)j * 16 * KDIM);
            bf[4 + j] = *reinterpret_cast<const f16x8*>(p + (size_t)j * 16 * KDIM + 32);
        }
    };
    auto compute = [&](int CUR) {
        const char* rb = (const char*)&As[0][0][0] + CUR * 32768;
        f16x8 a0[4], a1[4];
        #pragma unroll
        for (int i = 0; i < 4; ++i) {
            a0[i] = *reinterpret_cast<const f16x8*>(rb + rbyte0 + i * 16 * 128);
            a1[i] = *reinterpret_cast<const f16x8*>(rb + rbyte1 + i * 16 * 128);
        }
        __builtin_amdgcn_s_setprio(1);
        #pragma unroll
        for (int i = 0; i < 4; ++i)
            #pragma unroll
            for (int j = 0; j < 4; ++j)
                acc[i][j] = __builtin_amdgcn_mfma_f32_16x16x32_f16(a0[i], bfc[j], acc[i][j], 0, 0, 0);
        #pragma unroll
        for (int i = 0; i < 4; ++i)
            #pragma unroll
            for (int j = 0; j < 4; ++j)
                acc[i][j] = __builtin_amdgcn_mfma_f32_16x16x32_f16(a1[i], bfc[4 + j], acc[i][j], 0, 0, 0);
        __builtin_amdgcn_s_setprio(0);
    };

    // ---- prologue: stage tile 0 ----
    {
        float4 ar[8];
        stageIssue(ar, 0);
        loadB(bfc, 0);
        stageWrite(ar, 0);
        asm volatile("s_waitcnt lgkmcnt(0)" ::: "memory");
        __builtin_amdgcn_s_barrier();
        __builtin_amdgcn_sched_barrier(0);
    }

    #pragma unroll 1
    for (int tt = 0; tt < NKT; tt += 2) {
        { // t = tt, CUR = 0  (tt+1 < NKT always)
            float4 ar[8]; f16x8 bn[8];
            stageIssue(ar, tt + 1);
            loadB(bn, tt + 1);
            compute(0);
            stageWrite(ar, 1);
            #pragma unroll
            for (int j = 0; j < 8; ++j) bfc[j] = bn[j];
            asm volatile("s_waitcnt lgkmcnt(0)" ::: "memory");
            __builtin_amdgcn_s_barrier();
            __builtin_amdgcn_sched_barrier(0);
        }
        { // t = tt+1, CUR = 1
            const bool pre = (tt + 2 < NKT);
            float4 ar[8]; f16x8 bn[8];
            if (pre) { stageIssue(ar, tt + 2); loadB(bn, tt + 2); }
            compute(1);
            if (pre) {
                stageWrite(ar, 0);
                #pragma unroll
                for (int j = 0; j < 8; ++j) bfc[j] = bn[j];
            }
            asm volatile("s_waitcnt lgkmcnt(0)" ::: "memory");
            __builtin_amdgcn_s_barrier();
            __builtin_amdgcn_sched_barrier(0);
        }
    }

    // ---------------- epilogue ----------------
    // C/D frag: col = lane&15, row = (lane>>4)*4 + reg
    float sd[4], vwv[4];
    #pragma unroll
    for (int j = 0; j < 4; ++j) {
        const int col = colbase + wn * 64 + j * 16 + l15;
        sd[j]  = sdec[bidx * 1024 + col];
        vwv[j] = vw[col];
    }
    float psum[4][4];
    #pragma unroll
    for (int i = 0; i < 4; ++i)
        #pragma unroll
        for (int r = 0; r < 4; ++r) psum[i][r] = 0.f;

    #pragma unroll
    for (int i = 0; i < 4; ++i)
        #pragma unroll
        for (int j = 0; j < 4; ++j)
            #pragma unroll
            for (int r = 0; r < 4; ++r)
                psum[i][r] += tanhf(acc[i][j][r] + sd[j]) * vwv[j];

    #pragma unroll
    for (int i = 0; i < 4; ++i)
        #pragma unroll
        for (int r = 0; r < 4; ++r) {
            float s = psum[i][r];
            #pragma unroll
            for (int m = 1; m < 16; m <<= 1) s += __shfl_xor(s, m);
            psum[i][r] = s;
        }

    if (l15 == 0) {
        #pragma unroll
        for (int i = 0; i < 4; ++i)
            #pragma unroll
            for (int r = 0; r < 4; ++r)
                red[wn][wm * 64 + i * 16 + l4 * 4 + r] = psum[i][r];
    }
    __syncthreads();
    if (tid < 256) {
        part[(size_t)ct * M_TOT + rowbase + tid] = red[0][tid] + red[1][tid];
    }
}

// softmax over L per batch; mask==0 -> -1e10; sums the NCT partials.
__global__ __launch_bounds__(512) void softmax_kernel(
        const float* __restrict__ part, const int* __restrict__ mask,
        float* __restrict__ out) {
    int b = blockIdx.x;
    int tid = threadIdx.x;
    int lane = tid & 63, w = tid >> 6;
    __shared__ float sred[8];

    float vals[4];
    #pragma unroll
    for (int p = 0; p < 4; ++p) {
        int row = b * LSEQ + tid + p * 512;
        float val = 0.f;
        #pragma unroll
        for (int q = 0; q < NCT; ++q) val += part[(size_t)q * M_TOT + row];
        vals[p] = (mask[row] == 0) ? NEG_INF_F : val;
    }
    float mx = fmaxf(fmaxf(vals[0], vals[1]), fmaxf(vals[2], vals[3]));
    #pragma unroll
    for (int m = 1; m < 64; m <<= 1) mx = fmaxf(mx, __shfl_xor(mx, m));
    if (lane == 0) sred[w] = mx;
    __syncthreads();
    float gmax = sred[0];
    #pragma unroll
    for (int i = 1; i < 8; ++i) gmax = fmaxf(gmax, sred[i]);

    float es[4]; float ssum = 0.f;
    #pragma unroll
    for (int p = 0; p < 4; ++p) { es[p] = expf(vals[p] - gmax); ssum += es[p]; }
    #pragma unroll
    for (int m = 1; m < 64; m <<= 1) ssum += __shfl_xor(ssum, m);
    __syncthreads();
    if (lane == 0) sred[w] = ssum;
    __syncthreads();
    float gsum = 0.f;
    #pragma unroll
    for (int i = 0; i < 8; ++i) gsum += sred[i];
    float inv = 1.f / gsum;
    #pragma unroll
    for (int p = 0; p < 4; ++p)
        out[b * LSEQ + tid + p * 512] = es[p] * inv;
}

extern "C" void kernel_launch(void* const* d_in, const int* in_sizes, int n_in,
                              void* d_out, int out_size, void* d_ws, size_t ws_size,
                              hipStream_t stream) {
    const float* enc    = (const float*)d_in[0];
    const int*   mask   = (const int*)  d_in[1];
    const float* v      = (const float*)d_in[2];
    const float* attn_w = (const float*)d_in[3];
    const float* attn_b = (const float*)d_in[4];
    const float* v_w    = (const float*)d_in[5];
    float* out = (float*)d_out;

    char* ws = (char*)d_ws;
    f16*   we16 = (f16*)  (ws + WS_WE16_OFF);
    float* sdec = (float*)(ws + WS_SDEC_OFF);
    float* part = (float*)(ws + WS_PART_OFF);

    hipLaunchKernelGGL(wecvt_kernel, dim3(2048), dim3(256), 0, stream, attn_w, we16);
    hipLaunchKernelGGL(sdec_kernel,  dim3(4096), dim3(256), 0, stream, v, attn_w, attn_b, sdec);
    hipLaunchKernelGGL(fused_gemm,   dim3(1024), dim3(512), 0, stream, enc, we16, sdec, v_w, part);
    hipLaunchKernelGGL(softmax_kernel, dim3(16), dim3(512), 0, stream, part, mask, out);
}

// Round 5
// 242.538 us; speedup vs baseline: 2.2197x; 2.2197x over previous
//
#include <hip/hip_runtime.h>
#include <stdint.h>

#define H 1024
#define LSEQ 2048
#define M_TOT 32768          // B*L
#define KDIM 2048            // 2H
#define NKT 64               // K tiles of 32
#define NCT 8                // col tiles of 128
#define NEG_INF_F (-10000000000.0f)

typedef _Float16 f16;
typedef f16 f16x8 __attribute__((ext_vector_type(8)));
typedef float f32x4 __attribute__((ext_vector_type(4)));

// ---------------- ws layout ----------------
// [0, 64K)        sdec f32[16][1024]
// [64K, 64K+1M)   part f32[8][32768]
// [2M, 6M)        weT  tiled fp16 B  [8 ct][64 kt][512 granules x 16B]
// [6M, ...)       encT tiled fp16 A  [rtl][64 kt][1024 granules x 16B] (chunked)
#define WS_SDEC_OFF  0
#define WS_PART_OFF  (64u << 10)
#define WS_WET_OFF   (2u << 20)
#define WS_ENCT_OFF  (6u << 20)

__device__ inline void gload16(const void* g, void* l) {
    __builtin_amdgcn_global_load_lds(
        (const __attribute__((address_space(1))) void*)g,
        (__attribute__((address_space(3))) void*)l, 16, 0, 0);
}

// fast tanh(x)*s with sign fold: sign(x) applied to s
__device__ inline float tanh_mul(float x, float s) {
    float ax = __builtin_fabsf(x);
    float e  = __expf(-2.f * ax);                 // v_exp_f32 path
    float th = (1.f - e) * __builtin_amdgcn_rcpf(1.f + e);
    float sv = __uint_as_float(__float_as_uint(s) ^ (__float_as_uint(x) & 0x80000000u));
    return th * sv;
}

// W_e -> tiled/swizzled fp16. granule g: ct=g>>15, kt=(g>>9)&63, p=g&511,
// row=p>>2, slot=(p&3)^((row>>1)&3). 256 blocks x 256 thr x 4.
__global__ __launch_bounds__(256) void wecvt_tiled(const float* __restrict__ attn_w,
                                                   f16* __restrict__ weT) {
    int g = blockIdx.x * 1024 + threadIdx.x;
    #pragma unroll
    for (int q = 0; q < 4; ++q, g += 256) {
        int ct  = g >> 15;
        int rem = g & 32767;
        int kt  = rem >> 9;
        int p   = rem & 511;
        int row = p >> 2;
        int sl  = (p & 3) ^ ((row >> 1) & 3);
        const float* s = attn_w + (size_t)(ct * 128 + row) * 3072 + 1024 + kt * 32 + sl * 8;
        float4 a = *(const float4*)s;
        float4 b = *(const float4*)(s + 4);
        f16x8 h = { (f16)a.x,(f16)a.y,(f16)a.z,(f16)a.w,(f16)b.x,(f16)b.y,(f16)b.z,(f16)b.w };
        *(f16x8*)(weT + (size_t)g * 8) = h;
    }
}

// encoder_out -> tiled/swizzled fp16 (one row-chunk of rts row-tiles).
// granule g (chunk-local): rtl=g>>16, kt=(g>>10)&63, p=g&1023,
// row=p>>2, slot=(p&3)^((row>>1)&3). grid = rts*32, 8 granules/thread.
__global__ __launch_bounds__(256) void enccvt(const float* __restrict__ enc,
                                              f16* __restrict__ encT, int rt0) {
    int g = blockIdx.x * 2048 + threadIdx.x;
    #pragma unroll
    for (int q = 0; q < 8; ++q, g += 256) {
        int rtl = g >> 16;
        int rem = g & 65535;
        int kt  = rem >> 10;
        int p   = rem & 1023;
        int row = p >> 2;
        int sl  = (p & 3) ^ ((row >> 1) & 3);
        const float* s = enc + (size_t)((rt0 + rtl) * 256 + row) * 2048 + kt * 32 + sl * 8;
        float4 a = *(const float4*)s;
        float4 b = *(const float4*)(s + 4);
        f16x8 h = { (f16)a.x,(f16)a.y,(f16)a.z,(f16)a.w,(f16)b.x,(f16)b.y,(f16)b.z,(f16)b.w };
        *(f16x8*)(encT + (size_t)g * 8) = h;
    }
}

// score_dec[b][h] = attn_b[h] + sum_k v[b][k] * attn_w[h][k]
__global__ void sdec_kernel(const float* __restrict__ v,
                            const float* __restrict__ attn_w,
                            const float* __restrict__ attn_b,
                            float* __restrict__ sdec) {
    int gid  = blockIdx.x * 4 + (threadIdx.x >> 6);
    int lane = threadIdx.x & 63;
    int b = gid >> 10;
    int h = gid & 1023;
    const float* vr = v + b * 1024;
    const float* wr = attn_w + (size_t)h * 3072;
    float s = 0.f;
    #pragma unroll 4
    for (int k = lane; k < 1024; k += 64) s += vr[k] * wr[k];
    #pragma unroll
    for (int m = 1; m < 64; m <<= 1) s += __shfl_xor(s, m);
    if (lane == 0) sdec[b * 1024 + h] = s + attn_b[h];
}

// GEMM: 256x128 tile, 4 waves (each 64 rows x 128 cols, 4x8 frags), BK=32.
// Both operands staged via global_load_lds(16B) from pre-tiled fp16; LDS dbuf,
// one barrier per K-iter, stage(t+1) issued before compute(t).
__global__ __launch_bounds__(256, 2) void fused_gemm(
        const f16* __restrict__ encT,   // [rtl][64][1024 granules]
        const f16* __restrict__ weT,    // [8][64][512 granules]
        const float* __restrict__ sdec, // [16][1024]
        const float* __restrict__ vw,   // [1024]
        float* __restrict__ part,       // [NCT][32768]
        int rt0, int nblocks)
{
    // chunked XCD remap (nblocks % 8 == 0): consecutive logical on one XCD share A panel
    const int cpx = nblocks >> 3;
    const int logical = (blockIdx.x & 7) * cpx + (blockIdx.x >> 3);
    const int rtl = logical >> 3;
    const int ct  = logical & 7;

    const int tid = threadIdx.x;
    const int l15 = tid & 15;
    const int l4  = (tid >> 4) & 3;
    const int wv  = tid >> 6;        // 0..3, wave owns rows wv*64..+63, all 128 cols

    __shared__ f16 As[2][8192];      // 16KB per buf: [256 rows][4 slots x 16B], slot-swizzled
    __shared__ f16 Bs[2][4096];      // 8KB per buf:  [128 rows][4 slots]
    __shared__ float red[256];

    const char* aTile = (const char*)encT + ((size_t)rtl << 20);   // 64 tiles x 16KB
    const char* bTile = (const char*)weT  + ((size_t)ct  << 19);   // 64 tiles x 8KB

    // fragment read offsets (physical slot = l4 ^ ((row>>1)&3); row%16 == l15)
    const int sl   = l4 ^ ((l15 >> 1) & 3);
    const int aoff = (wv * 64 + l15) * 64 + sl * 16;   // + i*1024
    const int boff = l15 * 64 + sl * 16;               // + j*1024

    f32x4 acc[4][8] = {};

    auto stage = [&](int nb, int t) {
        const char* a = aTile + ((size_t)t << 14) + tid * 16;
        char* la = (char*)As[nb] + tid * 16;
        gload16(a,         la);
        gload16(a + 4096,  la + 4096);
        gload16(a + 8192,  la + 8192);
        gload16(a + 12288, la + 12288);
        const char* b = bTile + ((size_t)t << 13) + tid * 16;
        char* lb = (char*)Bs[nb] + tid * 16;
        gload16(b,        lb);
        gload16(b + 4096, lb + 4096);
    };
    auto compute = [&](int cb) {
        const char* la = (const char*)As[cb];
        const char* lb = (const char*)Bs[cb];
        f16x8 af[4], bf[8];
        #pragma unroll
        for (int i = 0; i < 4; ++i) af[i] = *(const f16x8*)(la + aoff + i * 1024);
        #pragma unroll
        for (int j = 0; j < 8; ++j) bf[j] = *(const f16x8*)(lb + boff + j * 1024);
        #pragma unroll
        for (int i = 0; i < 4; ++i)
            #pragma unroll
            for (int j = 0; j < 8; ++j)
                acc[i][j] = __builtin_amdgcn_mfma_f32_16x16x32_f16(af[i], bf[j], acc[i][j], 0, 0, 0);
    };

    stage(0, 0);
    #pragma unroll 1
    for (int t = 0; t < NKT; ++t) {
        const int cb = t & 1;
        __syncthreads();                    // drains staging of buf[cb]
        if (t + 1 < NKT) stage(cb ^ 1, t + 1);
        compute(cb);
    }

    // ---------------- epilogue ----------------
    // C/D frag: col = l15, row = l4*4 + r (within 16x16); global row = rowbase+wv*64+i*16+l4*4+r
    const int rowbase = (rt0 + rtl) * 256;
    const int colbase = ct * 128;
    const int bidx = (rt0 + rtl) >> 3;

    float sd[8], vs[8];
    #pragma unroll
    for (int j = 0; j < 8; ++j) {
        const int col = colbase + j * 16 + l15;
        sd[j] = sdec[bidx * 1024 + col];
        vs[j] = vw[col];
    }
    float psum[4][4] = {};
    #pragma unroll
    for (int i = 0; i < 4; ++i)
        #pragma unroll
        for (int j = 0; j < 8; ++j)
            #pragma unroll
            for (int r = 0; r < 4; ++r)
                psum[i][r] += tanh_mul(acc[i][j][r] + sd[j], vs[j]);

    #pragma unroll
    for (int i = 0; i < 4; ++i)
        #pragma unroll
        for (int r = 0; r < 4; ++r) {
            float s = psum[i][r];
            s += __shfl_xor(s, 1); s += __shfl_xor(s, 2);
            s += __shfl_xor(s, 4); s += __shfl_xor(s, 8);
            psum[i][r] = s;
        }

    if (l15 == 0) {
        #pragma unroll
        for (int i = 0; i < 4; ++i)
            #pragma unroll
            for (int r = 0; r < 4; ++r)
                red[wv * 64 + i * 16 + l4 * 4 + r] = psum[i][r];
    }
    __syncthreads();
    part[(size_t)ct * M_TOT + rowbase + tid] = red[tid];
}

// softmax over L per batch; mask==0 -> -1e10; sums the NCT partials.
__global__ __launch_bounds__(512) void softmax_kernel(
        const float* __restrict__ part, const int* __restrict__ mask,
        float* __restrict__ out) {
    int b = blockIdx.x;
    int tid = threadIdx.x;
    int lane = tid & 63, w = tid >> 6;
    __shared__ float sred[8];

    float vals[4];
    #pragma unroll
    for (int p = 0; p < 4; ++p) {
        int row = b * LSEQ + tid + p * 512;
        float val = 0.f;
        #pragma unroll
        for (int q = 0; q < NCT; ++q) val += part[(size_t)q * M_TOT + row];
        vals[p] = (mask[row] == 0) ? NEG_INF_F : val;
    }
    float mx = fmaxf(fmaxf(vals[0], vals[1]), fmaxf(vals[2], vals[3]));
    #pragma unroll
    for (int m = 1; m < 64; m <<= 1) mx = fmaxf(mx, __shfl_xor(mx, m));
    if (lane == 0) sred[w] = mx;
    __syncthreads();
    float gmax = sred[0];
    #pragma unroll
    for (int i = 1; i < 8; ++i) gmax = fmaxf(gmax, sred[i]);

    float es[4]; float ssum = 0.f;
    #pragma unroll
    for (int p = 0; p < 4; ++p) { es[p] = expf(vals[p] - gmax); ssum += es[p]; }
    #pragma unroll
    for (int m = 1; m < 64; m <<= 1) ssum += __shfl_xor(ssum, m);
    __syncthreads();
    if (lane == 0) sred[w] = ssum;
    __syncthreads();
    float gsum = 0.f;
    #pragma unroll
    for (int i = 0; i < 8; ++i) gsum += sred[i];
    float inv = 1.f / gsum;
    #pragma unroll
    for (int p = 0; p < 4; ++p)
        out[b * LSEQ + tid + p * 512] = es[p] * inv;
}

extern "C" void kernel_launch(void* const* d_in, const int* in_sizes, int n_in,
                              void* d_out, int out_size, void* d_ws, size_t ws_size,
                              hipStream_t stream) {
    const float* enc    = (const float*)d_in[0];
    const int*   mask   = (const int*)  d_in[1];
    const float* v      = (const float*)d_in[2];
    const float* attn_w = (const float*)d_in[3];
    const float* attn_b = (const float*)d_in[4];
    const float* v_w    = (const float*)d_in[5];
    float* out = (float*)d_out;

    char* ws = (char*)d_ws;
    float* sdec = (float*)(ws + WS_SDEC_OFF);
    float* part = (float*)(ws + WS_PART_OFF);
    f16*   weT  = (f16*)  (ws + WS_WET_OFF);
    f16*   encT = (f16*)  (ws + WS_ENCT_OFF);

    hipLaunchKernelGGL(wecvt_tiled, dim3(256),  dim3(256), 0, stream, attn_w, weT);
    hipLaunchKernelGGL(sdec_kernel, dim3(4096), dim3(256), 0, stream, v, attn_w, attn_b, sdec);

    // row-chunking: each row-tile (256 rows) needs 1 MB of encT
    size_t cap = (ws_size > WS_ENCT_OFF) ? (ws_size - WS_ENCT_OFF) : 0;
    int crt = (int)(cap >> 20);
    if (crt > 128) crt = 128;
    if (crt < 1)   crt = 1;
    for (int rt0 = 0; rt0 < 128; rt0 += crt) {
        int rts = (128 - rt0 < crt) ? (128 - rt0) : crt;
        hipLaunchKernelGGL(enccvt,     dim3(rts * 32), dim3(256), 0, stream, enc, encT, rt0);
        hipLaunchKernelGGL(fused_gemm, dim3(rts * 8),  dim3(256), 0, stream,
                           encT, weT, sdec, v_w, part, rt0, rts * 8);
    }
    hipLaunchKernelGGL(softmax_kernel, dim3(16), dim3(512), 0, stream, part, mask, out);
}